// Round 1
// baseline (220.107 us; speedup 1.0000x reference)
//
#include <hip/hip_runtime.h>
#include <hip/hip_bf16.h>

using bf16 = __hip_bfloat16;
typedef __attribute__((ext_vector_type(8))) short frag8;   // 8 bf16 (4 VGPRs)
typedef __attribute__((ext_vector_type(4))) float f32x4;   // 4 fp32 acc

constexpr int   H_   = 1024;               // N_EMBD
constexpr int   B_   = 8;                  // BATCH
constexpr int   T_   = 2048;
constexpr int   K_   = H_;
constexpr int   N_   = H_;
constexpr long  M_   = (long)B_ * T_;      // 16384
constexpr int   SEG  = 8;
constexpr int   TSEG = T_ / SEG;           // 256
constexpr int   NCH  = B_ * H_;            // 8192 channels

// ---------------- a = sigmoid(raw_a) ----------------
__global__ __launch_bounds__(256) void k_sigmoid(const float* __restrict__ raw,
                                                 float* __restrict__ a_sig) {
  int i = blockIdx.x * 256 + threadIdx.x;
  if (i < H_) a_sig[i] = 1.0f / (1.0f + expf(-raw[i]));
}

// ---------------- fp32 -> bf16 convert (x then B) ----------------
__device__ __forceinline__ unsigned short f2bf(float f) {
  bf16 b = __float2bfloat16(f);
  return *reinterpret_cast<unsigned short*>(&b);
}

__global__ __launch_bounds__(256) void k_convert(const float* __restrict__ x,
                                                 const float* __restrict__ Bm,
                                                 unsigned short* __restrict__ xb,
                                                 unsigned short* __restrict__ Bb) {
  const long NX4 = (M_ * K_) / 4;             // 4194304
  const long NB4 = ((long)N_ * K_) / 4;       // 262144
  long t = (long)blockIdx.x * 256 + threadIdx.x;
  const float* src; unsigned short* dst;
  if (t < NX4) { src = x; dst = xb; }
  else { t -= NX4; if (t >= NB4) return; src = Bm; dst = Bb; }
  long i = t * 4;
  float4 v = *reinterpret_cast<const float4*>(src + i);
  short4 o;
  o.x = (short)f2bf(v.x);
  o.y = (short)f2bf(v.y);
  o.z = (short)f2bf(v.z);
  o.w = (short)f2bf(v.w);
  *reinterpret_cast<short4*>(dst + i) = o;
}

// ---------------- bf16 GEMM (m97 structure): C[m][n] = sum_k A[m,k]*B[n,k] ----------------
// A: [M,K] bf16 row-major (K contiguous), Bb: [N,K] bf16 row-major — "BT" gemm.
__global__ __launch_bounds__(256) void k_gemm(const unsigned short* __restrict__ A,
                                              const unsigned short* __restrict__ Bb,
                                              float* __restrict__ C) {
  constexpr int BK = 32;
  __shared__ __align__(16) unsigned short lA[128 * BK];   // 8 KiB
  __shared__ __align__(16) unsigned short lB[128 * BK];   // 8 KiB
  const int tid  = threadIdx.x;
  const int lane = tid & 63;
  const int wave = tid >> 6;
  const long m0 = (long)blockIdx.x * 128;
  const long n0 = (long)blockIdx.y * 128;
  const int wm = (wave >> 1) * 64;   // wave sub-tile origin (2x2 waves of 64x64)
  const int wn = (wave & 1) * 64;
  const int quad = lane >> 4;
  const int l16  = lane & 15;

  // staging: thread t loads 16B (8 bf16): row = t>>2, col8 = (t&3)*8
  const unsigned short* gA = A  + (m0 + (tid >> 2)) * K_ + (tid & 3) * 8;
  const unsigned short* gB = Bb + (n0 + (tid >> 2)) * K_ + (tid & 3) * 8;
  // LDS dest is wave-uniform base + lane*16B; layout = row-major [128][32]
  unsigned short* sA = &lA[(tid & ~63) * 8];
  unsigned short* sB = &lB[(tid & ~63) * 8];

  f32x4 acc[4][4];
  #pragma unroll
  for (int i = 0; i < 4; i++)
    #pragma unroll
    for (int j = 0; j < 4; j++)
      acc[i][j] = f32x4{0.f, 0.f, 0.f, 0.f};

  for (int k0 = 0; k0 < K_; k0 += BK) {
    __builtin_amdgcn_global_load_lds(
        (const __attribute__((address_space(1))) void*)(gA + k0),
        (__attribute__((address_space(3))) void*)sA, 16, 0, 0);
    __builtin_amdgcn_global_load_lds(
        (const __attribute__((address_space(1))) void*)(gA + 64 * K_ + k0),
        (__attribute__((address_space(3))) void*)(sA + 64 * BK), 16, 0, 0);
    __builtin_amdgcn_global_load_lds(
        (const __attribute__((address_space(1))) void*)(gB + k0),
        (__attribute__((address_space(3))) void*)sB, 16, 0, 0);
    __builtin_amdgcn_global_load_lds(
        (const __attribute__((address_space(1))) void*)(gB + 64 * K_ + k0),
        (__attribute__((address_space(3))) void*)(sB + 64 * BK), 16, 0, 0);
    __syncthreads();   // compiler emits vmcnt(0) drain before barrier

    frag8 af[4], bfr[4];
    #pragma unroll
    for (int i = 0; i < 4; i++) {
      af[i]  = *reinterpret_cast<const frag8*>(&lA[(wm + i * 16 + l16) * BK + quad * 8]);
      bfr[i] = *reinterpret_cast<const frag8*>(&lB[(wn + i * 16 + l16) * BK + quad * 8]);
    }
    #pragma unroll
    for (int i = 0; i < 4; i++)
      #pragma unroll
      for (int j = 0; j < 4; j++)
        acc[i][j] = __builtin_amdgcn_mfma_f32_16x16x32_bf16(af[i], bfr[j], acc[i][j], 0, 0, 0);
    __syncthreads();
  }

  // C/D layout (m89-verified): col = lane&15, row = (lane>>4)*4 + reg
  #pragma unroll
  for (int i = 0; i < 4; i++)
    #pragma unroll
    for (int j = 0; j < 4; j++) {
      long r0 = m0 + wm + i * 16 + quad * 4;
      long c0 = n0 + wn + j * 16 + l16;
      #pragma unroll
      for (int r = 0; r < 4; r++)
        C[(r0 + r) * N_ + c0] = acc[i][j][r];
    }
}

// ---------------- scan phase 1: per-segment local end-states (zero init) ----------------
__global__ __launch_bounds__(256) void k_seg_ends(const float* __restrict__ u,
                                                  const float* __restrict__ a_sig,
                                                  float* __restrict__ E) {
  int g = blockIdx.x * 256 + threadIdx.x;   // 0..65535
  int c = g & (NCH - 1);                    // channel = b*H + h
  int s = g >> 13;                          // segment
  int h = c & (H_ - 1);
  int b = c >> 10;
  float a = a_sig[h];
  const float* p = u + (long)b * T_ * H_ + (long)s * TSEG * H_ + h;
  float e = 0.f;
  #pragma unroll 8
  for (int t = 0; t < TSEG; t++) { e = fmaf(e, a, *p); p += H_; }
  E[g] = e;
}

// ---------------- scan phase 2: carry chain across segments ----------------
__global__ __launch_bounds__(256) void k_carries(const float* __restrict__ E,
                                                 const float* __restrict__ h0,
                                                 const float* __restrict__ a_sig,
                                                 float* __restrict__ Cc) {
  int c = blockIdx.x * 256 + threadIdx.x;   // 0..8191
  if (c >= NCH) return;
  float a = a_sig[c & (H_ - 1)];
  float aL = a;
  #pragma unroll
  for (int i = 0; i < 8; i++) aL *= aL;     // a^256
  float carry = h0[c];
  #pragma unroll
  for (int s = 0; s < SEG; s++) {
    Cc[s * NCH + c] = carry;                // state entering segment s
    carry = fmaf(aL, carry, E[s * NCH + c]);
  }
}

// ---------------- scan phase 3: final scan with carry-in, in-place on d_out ----------------
__global__ __launch_bounds__(256) void k_scan(float* __restrict__ u,
                                              const float* __restrict__ Cc,
                                              const float* __restrict__ a_sig) {
  int g = blockIdx.x * 256 + threadIdx.x;
  int c = g & (NCH - 1);
  int s = g >> 13;
  int h = c & (H_ - 1);
  int b = c >> 10;
  float a = a_sig[h];
  float hs = Cc[s * NCH + c];
  float* p = u + (long)b * T_ * H_ + (long)s * TSEG * H_ + h;
  #pragma unroll 8
  for (int t = 0; t < TSEG; t++) { hs = fmaf(hs, a, *p); *p = hs; p += H_; }
}

extern "C" void kernel_launch(void* const* d_in, const int* in_sizes, int n_in,
                              void* d_out, int out_size, void* d_ws, size_t ws_size,
                              hipStream_t stream) {
  const float* x    = (const float*)d_in[0];   // [8,2048,1024]
  const float* rawa = (const float*)d_in[1];   // [1024]
  const float* Bm   = (const float*)d_in[2];   // [1024,1024]
  const float* h0   = (const float*)d_in[3];   // [8,1024]
  float* u = (float*)d_out;                    // u then y, in place

  char* w = (char*)d_ws;
  unsigned short* xb = (unsigned short*)w;                               // 32 MiB
  unsigned short* Bb = (unsigned short*)(w + 33554432);                  // 2 MiB
  float* a_sig = (float*)(w + 33554432 + 2097152);                       // 4 KiB
  float* E     = (float*)(w + 33554432 + 2097152 + 4096);                // 256 KiB
  float* Cc    = (float*)(w + 33554432 + 2097152 + 4096 + 262144);       // 256 KiB

  hipLaunchKernelGGL(k_sigmoid, dim3(4), dim3(256), 0, stream, rawa, a_sig);
  hipLaunchKernelGGL(k_convert, dim3(17408), dim3(256), 0, stream, x, Bm, xb, Bb);
  hipLaunchKernelGGL(k_gemm, dim3(128, 8), dim3(256), 0, stream, xb, Bb, u);
  hipLaunchKernelGGL(k_seg_ends, dim3(256), dim3(256), 0, stream, u, a_sig, E);
  hipLaunchKernelGGL(k_carries, dim3(32), dim3(256), 0, stream, E, h0, a_sig, Cc);
  hipLaunchKernelGGL(k_scan, dim3(256), dim3(256), 0, stream, u, Cc, a_sig);
}

// Round 2
// 201.840 us; speedup vs baseline: 1.0905x; 1.0905x over previous
//
#include <hip/hip_runtime.h>
#include <hip/hip_bf16.h>

using bf16 = __hip_bfloat16;
typedef __attribute__((ext_vector_type(8))) short frag8;   // 8 bf16 (4 VGPRs)
typedef __attribute__((ext_vector_type(4))) float f32x4;   // 4 fp32 acc

constexpr int   H_   = 1024;               // N_EMBD
constexpr int   B_   = 8;                  // BATCH
constexpr int   T_   = 2048;
constexpr int   K_   = H_;
constexpr int   N_   = H_;
constexpr long  M_   = (long)B_ * T_;      // 16384
constexpr int   SEG  = 32;                 // segments per sequence (was 8)
constexpr int   TSEG = T_ / SEG;           // 64
constexpr int   NCH  = B_ * H_;            // 8192 channels

// ---------------- fp32 -> bf16 convert (x then B) + fused sigmoid ----------------
__device__ __forceinline__ unsigned short f2bf(float f) {
  bf16 b = __float2bfloat16(f);
  return *reinterpret_cast<unsigned short*>(&b);
}

__global__ __launch_bounds__(256) void k_convert(const float* __restrict__ x,
                                                 const float* __restrict__ Bm,
                                                 const float* __restrict__ raw,
                                                 unsigned short* __restrict__ xb,
                                                 unsigned short* __restrict__ Bb,
                                                 float* __restrict__ a_sig) {
  const long NX4 = (M_ * K_) / 4;             // 4194304
  const long NB4 = ((long)N_ * K_) / 4;       // 262144
  long t = (long)blockIdx.x * 256 + threadIdx.x;
  const float* src; unsigned short* dst;
  if (t < NX4) { src = x; dst = xb; }
  else if (t < NX4 + NB4) { t -= NX4; src = Bm; dst = Bb; }
  else {
    // sigmoid tail: 256 quads cover H_=1024
    long q = t - NX4 - NB4;
    if (q >= H_ / 4) return;
    float4 v = *reinterpret_cast<const float4*>(raw + q * 4);
    float4 o;
    o.x = 1.0f / (1.0f + expf(-v.x));
    o.y = 1.0f / (1.0f + expf(-v.y));
    o.z = 1.0f / (1.0f + expf(-v.z));
    o.w = 1.0f / (1.0f + expf(-v.w));
    *reinterpret_cast<float4*>(a_sig + q * 4) = o;
    return;
  }
  long i = t * 4;
  float4 v = *reinterpret_cast<const float4*>(src + i);
  short4 o;
  o.x = (short)f2bf(v.x);
  o.y = (short)f2bf(v.y);
  o.z = (short)f2bf(v.z);
  o.w = (short)f2bf(v.w);
  *reinterpret_cast<short4*>(dst + i) = o;
}

// ---------------- bf16 GEMM (m97 structure): C[m][n] = sum_k A[m,k]*B[n,k] ----------------
__global__ __launch_bounds__(256) void k_gemm(const unsigned short* __restrict__ A,
                                              const unsigned short* __restrict__ Bb,
                                              float* __restrict__ C) {
  constexpr int BK = 32;
  __shared__ __align__(16) unsigned short lA[128 * BK];   // 8 KiB
  __shared__ __align__(16) unsigned short lB[128 * BK];   // 8 KiB
  const int tid  = threadIdx.x;
  const int lane = tid & 63;
  const int wave = tid >> 6;
  const long m0 = (long)blockIdx.x * 128;
  const long n0 = (long)blockIdx.y * 128;
  const int wm = (wave >> 1) * 64;
  const int wn = (wave & 1) * 64;
  const int quad = lane >> 4;
  const int l16  = lane & 15;

  const unsigned short* gA = A  + (m0 + (tid >> 2)) * K_ + (tid & 3) * 8;
  const unsigned short* gB = Bb + (n0 + (tid >> 2)) * K_ + (tid & 3) * 8;
  unsigned short* sA = &lA[(tid & ~63) * 8];
  unsigned short* sB = &lB[(tid & ~63) * 8];

  f32x4 acc[4][4];
  #pragma unroll
  for (int i = 0; i < 4; i++)
    #pragma unroll
    for (int j = 0; j < 4; j++)
      acc[i][j] = f32x4{0.f, 0.f, 0.f, 0.f};

  for (int k0 = 0; k0 < K_; k0 += BK) {
    __builtin_amdgcn_global_load_lds(
        (const __attribute__((address_space(1))) void*)(gA + k0),
        (__attribute__((address_space(3))) void*)sA, 16, 0, 0);
    __builtin_amdgcn_global_load_lds(
        (const __attribute__((address_space(1))) void*)(gA + 64 * K_ + k0),
        (__attribute__((address_space(3))) void*)(sA + 64 * BK), 16, 0, 0);
    __builtin_amdgcn_global_load_lds(
        (const __attribute__((address_space(1))) void*)(gB + k0),
        (__attribute__((address_space(3))) void*)sB, 16, 0, 0);
    __builtin_amdgcn_global_load_lds(
        (const __attribute__((address_space(1))) void*)(gB + 64 * K_ + k0),
        (__attribute__((address_space(3))) void*)(sB + 64 * BK), 16, 0, 0);
    __syncthreads();

    frag8 af[4], bfr[4];
    #pragma unroll
    for (int i = 0; i < 4; i++) {
      af[i]  = *reinterpret_cast<const frag8*>(&lA[(wm + i * 16 + l16) * BK + quad * 8]);
      bfr[i] = *reinterpret_cast<const frag8*>(&lB[(wn + i * 16 + l16) * BK + quad * 8]);
    }
    #pragma unroll
    for (int i = 0; i < 4; i++)
      #pragma unroll
      for (int j = 0; j < 4; j++)
        acc[i][j] = __builtin_amdgcn_mfma_f32_16x16x32_bf16(af[i], bfr[j], acc[i][j], 0, 0, 0);
    __syncthreads();
  }

  #pragma unroll
  for (int i = 0; i < 4; i++)
    #pragma unroll
    for (int j = 0; j < 4; j++) {
      long r0 = m0 + wm + i * 16 + quad * 4;
      long c0 = n0 + wn + j * 16 + l16;
      #pragma unroll
      for (int r = 0; r < 4; r++)
        C[(r0 + r) * N_ + c0] = acc[i][j][r];
    }
}

// ---------------- scan phase 1: per-segment local end-states (zero init) ----------------
__global__ __launch_bounds__(256) void k_seg_ends(const float* __restrict__ u,
                                                  const float* __restrict__ a_sig,
                                                  float* __restrict__ E) {
  int g = blockIdx.x * 256 + threadIdx.x;   // 0 .. NCH*SEG-1 = 262143
  int c = g & (NCH - 1);                    // channel = b*H + h
  int s = g >> 13;                          // segment 0..31
  int h = c & (H_ - 1);
  int b = c >> 10;
  float a = a_sig[h];
  const float* p = u + (long)b * T_ * H_ + (long)s * TSEG * H_ + h;
  float e = 0.f;
  #pragma unroll
  for (int t = 0; t < TSEG; t++) { e = fmaf(e, a, p[t * H_]); }
  E[g] = e;
}

// ---------------- scan phase 2: carry chain across segments ----------------
__global__ __launch_bounds__(256) void k_carries(const float* __restrict__ E,
                                                 const float* __restrict__ h0,
                                                 const float* __restrict__ a_sig,
                                                 float* __restrict__ Cc) {
  int c = blockIdx.x * 256 + threadIdx.x;   // 0..8191
  if (c >= NCH) return;
  float a = a_sig[c & (H_ - 1)];
  float aL = a;
  #pragma unroll
  for (int i = 0; i < 6; i++) aL *= aL;     // a^64 = a^TSEG
  float carry = h0[c];
  #pragma unroll
  for (int s = 0; s < SEG; s++) {
    Cc[s * NCH + c] = carry;                // state entering segment s
    carry = fmaf(aL, carry, E[s * NCH + c]);
  }
}

// ---------------- scan phase 3: final scan with carry-in, in-place on d_out ----------------
__global__ __launch_bounds__(256) void k_scan(float* __restrict__ u,
                                              const float* __restrict__ Cc,
                                              const float* __restrict__ a_sig) {
  int g = blockIdx.x * 256 + threadIdx.x;
  int c = g & (NCH - 1);
  int s = g >> 13;
  int h = c & (H_ - 1);
  int b = c >> 10;
  float a = a_sig[h];
  float hs = Cc[s * NCH + c];
  float* p = u + (long)b * T_ * H_ + (long)s * TSEG * H_ + h;
  #pragma unroll
  for (int t = 0; t < TSEG; t++) { hs = fmaf(hs, a, p[t * H_]); p[t * H_] = hs; }
}

extern "C" void kernel_launch(void* const* d_in, const int* in_sizes, int n_in,
                              void* d_out, int out_size, void* d_ws, size_t ws_size,
                              hipStream_t stream) {
  const float* x    = (const float*)d_in[0];   // [8,2048,1024]
  const float* rawa = (const float*)d_in[1];   // [1024]
  const float* Bm   = (const float*)d_in[2];   // [1024,1024]
  const float* h0   = (const float*)d_in[3];   // [8,1024]
  float* u = (float*)d_out;                    // u then y, in place

  char* w = (char*)d_ws;
  unsigned short* xb = (unsigned short*)w;                               // 32 MiB
  unsigned short* Bb = (unsigned short*)(w + 33554432);                  // 2 MiB
  float* a_sig = (float*)(w + 33554432 + 2097152);                       // 4 KiB
  float* E     = (float*)(w + 33554432 + 2097152 + 4096);                // 1 MiB
  float* Cc    = (float*)(w + 33554432 + 2097152 + 4096 + 1048576);      // 1 MiB

  // convert + sigmoid: NX4 + NB4 + 256 quads = 4456704+256 threads -> 17409 blocks
  hipLaunchKernelGGL(k_convert, dim3(17409), dim3(256), 0, stream, x, Bm, rawa, xb, Bb, a_sig);
  hipLaunchKernelGGL(k_gemm, dim3(128, 8), dim3(256), 0, stream, xb, Bb, u);
  hipLaunchKernelGGL(k_seg_ends, dim3(NCH * SEG / 256), dim3(256), 0, stream, u, a_sig, E);
  hipLaunchKernelGGL(k_carries, dim3(32), dim3(256), 0, stream, E, h0, a_sig, Cc);
  hipLaunchKernelGGL(k_scan, dim3(NCH * SEG / 256), dim3(256), 0, stream, u, Cc, a_sig);
}

// Round 6
// 200.306 us; speedup vs baseline: 1.0989x; 1.0077x over previous
//
#include <hip/hip_runtime.h>
#include <hip/hip_bf16.h>

using bf16 = __hip_bfloat16;
typedef __attribute__((ext_vector_type(8))) short frag8;   // 8 bf16 (4 VGPRs)
typedef __attribute__((ext_vector_type(4))) float f32x4;   // 4 fp32 acc

constexpr int   H_   = 1024;               // N_EMBD
constexpr int   B_   = 8;                  // BATCH
constexpr int   T_   = 2048;
constexpr int   K_   = H_;
constexpr int   N_   = H_;
constexpr long  M_   = (long)B_ * T_;      // 16384
constexpr int   SEG  = 32;                 // segments per sequence (R2 value)
constexpr int   TSEG = T_ / SEG;           // 64
constexpr int   NCH  = B_ * H_;            // 8192 channels
constexpr int   NVC  = NCH / 4;            // 2048 vec4-channels

// ---------------- fp32 -> bf16 convert (x then B) + fused sigmoid (R2 version) ----------------
__device__ __forceinline__ unsigned short f2bf(float f) {
  bf16 b = __float2bfloat16(f);
  return *reinterpret_cast<unsigned short*>(&b);
}

__global__ __launch_bounds__(256) void k_convert(const float* __restrict__ x,
                                                 const float* __restrict__ Bm,
                                                 const float* __restrict__ raw,
                                                 unsigned short* __restrict__ xb,
                                                 unsigned short* __restrict__ Bb,
                                                 float* __restrict__ a_sig) {
  const long NX4 = (M_ * K_) / 4;             // 4194304
  const long NB4 = ((long)N_ * K_) / 4;       // 262144
  long t = (long)blockIdx.x * 256 + threadIdx.x;
  const float* src; unsigned short* dst;
  if (t < NX4) { src = x; dst = xb; }
  else if (t < NX4 + NB4) { t -= NX4; src = Bm; dst = Bb; }
  else {
    // sigmoid tail: 256 quads cover H_=1024
    long q = t - NX4 - NB4;
    if (q >= H_ / 4) return;
    float4 v = *reinterpret_cast<const float4*>(raw + q * 4);
    float4 o;
    o.x = 1.0f / (1.0f + expf(-v.x));
    o.y = 1.0f / (1.0f + expf(-v.y));
    o.z = 1.0f / (1.0f + expf(-v.z));
    o.w = 1.0f / (1.0f + expf(-v.w));
    *reinterpret_cast<float4*>(a_sig + q * 4) = o;
    return;
  }
  long i = t * 4;
  float4 v = *reinterpret_cast<const float4*>(src + i);
  short4 o;
  o.x = (short)f2bf(v.x);
  o.y = (short)f2bf(v.y);
  o.z = (short)f2bf(v.z);
  o.w = (short)f2bf(v.w);
  *reinterpret_cast<short4*>(dst + i) = o;
}

// ---------------- bf16 GEMM (m97 structure): C[m][n] = sum_k A[m,k]*B[n,k] ----------------
__global__ __launch_bounds__(256) void k_gemm(const unsigned short* __restrict__ A,
                                              const unsigned short* __restrict__ Bb,
                                              float* __restrict__ C) {
  constexpr int BK = 32;
  __shared__ __align__(16) unsigned short lA[128 * BK];   // 8 KiB
  __shared__ __align__(16) unsigned short lB[128 * BK];   // 8 KiB
  const int tid  = threadIdx.x;
  const int lane = tid & 63;
  const int wave = tid >> 6;
  const long m0 = (long)blockIdx.x * 128;
  const long n0 = (long)blockIdx.y * 128;
  const int wm = (wave >> 1) * 64;
  const int wn = (wave & 1) * 64;
  const int quad = lane >> 4;
  const int l16  = lane & 15;

  const unsigned short* gA = A  + (m0 + (tid >> 2)) * K_ + (tid & 3) * 8;
  const unsigned short* gB = Bb + (n0 + (tid >> 2)) * K_ + (tid & 3) * 8;
  unsigned short* sA = &lA[(tid & ~63) * 8];
  unsigned short* sB = &lB[(tid & ~63) * 8];

  f32x4 acc[4][4];
  #pragma unroll
  for (int i = 0; i < 4; i++)
    #pragma unroll
    for (int j = 0; j < 4; j++)
      acc[i][j] = f32x4{0.f, 0.f, 0.f, 0.f};

  for (int k0 = 0; k0 < K_; k0 += BK) {
    __builtin_amdgcn_global_load_lds(
        (const __attribute__((address_space(1))) void*)(gA + k0),
        (__attribute__((address_space(3))) void*)sA, 16, 0, 0);
    __builtin_amdgcn_global_load_lds(
        (const __attribute__((address_space(1))) void*)(gA + 64 * K_ + k0),
        (__attribute__((address_space(3))) void*)(sA + 64 * BK), 16, 0, 0);
    __builtin_amdgcn_global_load_lds(
        (const __attribute__((address_space(1))) void*)(gB + k0),
        (__attribute__((address_space(3))) void*)sB, 16, 0, 0);
    __builtin_amdgcn_global_load_lds(
        (const __attribute__((address_space(1))) void*)(gB + 64 * K_ + k0),
        (__attribute__((address_space(3))) void*)(sB + 64 * BK), 16, 0, 0);
    __syncthreads();

    frag8 af[4], bfr[4];
    #pragma unroll
    for (int i = 0; i < 4; i++) {
      af[i]  = *reinterpret_cast<const frag8*>(&lA[(wm + i * 16 + l16) * BK + quad * 8]);
      bfr[i] = *reinterpret_cast<const frag8*>(&lB[(wn + i * 16 + l16) * BK + quad * 8]);
    }
    #pragma unroll
    for (int i = 0; i < 4; i++)
      #pragma unroll
      for (int j = 0; j < 4; j++)
        acc[i][j] = __builtin_amdgcn_mfma_f32_16x16x32_bf16(af[i], bfr[j], acc[i][j], 0, 0, 0);
    __syncthreads();
  }

  #pragma unroll
  for (int i = 0; i < 4; i++)
    #pragma unroll
    for (int j = 0; j < 4; j++) {
      long r0 = m0 + wm + i * 16 + quad * 4;
      long c0 = n0 + wn + j * 16 + l16;
      #pragma unroll
      for (int r = 0; r < 4; r++)
        C[(r0 + r) * N_ + c0] = acc[i][j][r];
    }
}

// ---------------- scan phase 1: per-segment local end-states, vec4 channels ----------------
__global__ __launch_bounds__(256) void k_seg_ends(const float* __restrict__ u,
                                                  const float* __restrict__ a_sig,
                                                  float* __restrict__ E) {
  int g = blockIdx.x * 256 + threadIdx.x;   // 0 .. NVC*SEG-1 = 65535
  int vc = g & (NVC - 1);                   // 0..2047 (vec4 channel)
  int s  = g >> 11;                         // segment 0..31
  int b  = vc >> 8;                         // batch
  int h4 = (vc & 255) * 4;                  // first of 4 h-channels
  float4 a = *reinterpret_cast<const float4*>(a_sig + h4);
  const float* base = u + (long)b * T_ * H_ + (long)s * TSEG * H_ + h4;
  float4 e = {0.f, 0.f, 0.f, 0.f};
  for (int t = 0; t < TSEG; t++) {
    float4 v = *reinterpret_cast<const float4*>(base + (long)t * H_);
    e.x = fmaf(e.x, a.x, v.x);
    e.y = fmaf(e.y, a.y, v.y);
    e.z = fmaf(e.z, a.z, v.z);
    e.w = fmaf(e.w, a.w, v.w);
  }
  // E[s*NCH + 4*vc + j] == E[4*g + j]  (contiguous float4)
  *reinterpret_cast<float4*>(E + (long)g * 4) = e;
}

// ---------------- scan phase 2: carry chain across segments (R2 version) ----------------
__global__ __launch_bounds__(256) void k_carries(const float* __restrict__ E,
                                                 const float* __restrict__ h0,
                                                 const float* __restrict__ a_sig,
                                                 float* __restrict__ Cc) {
  int c = blockIdx.x * 256 + threadIdx.x;   // 0..8191
  if (c >= NCH) return;
  float a = a_sig[c & (H_ - 1)];
  float aL = a;
  #pragma unroll
  for (int i = 0; i < 6; i++) aL *= aL;     // a^64 = a^TSEG
  float carry = h0[c];
  #pragma unroll
  for (int s = 0; s < SEG; s++) {
    Cc[s * NCH + c] = carry;                // state entering segment s
    carry = fmaf(aL, carry, E[s * NCH + c]);
  }
}

// ---------------- scan phase 3: final scan with carry-in, in-place, vec4 ----------------
__global__ __launch_bounds__(256) void k_scan(float* __restrict__ u,
                                              const float* __restrict__ Cc,
                                              const float* __restrict__ a_sig) {
  int g = blockIdx.x * 256 + threadIdx.x;
  int vc = g & (NVC - 1);
  int s  = g >> 11;
  int b  = vc >> 8;
  int h4 = (vc & 255) * 4;
  float4 a = *reinterpret_cast<const float4*>(a_sig + h4);
  float4 hs = *reinterpret_cast<const float4*>(Cc + (long)g * 4);
  float* base = u + (long)b * T_ * H_ + (long)s * TSEG * H_ + h4;
  for (int t = 0; t < TSEG; t++) {
    float4 v = *reinterpret_cast<const float4*>(base + (long)t * H_);
    hs.x = fmaf(hs.x, a.x, v.x);
    hs.y = fmaf(hs.y, a.y, v.y);
    hs.z = fmaf(hs.z, a.z, v.z);
    hs.w = fmaf(hs.w, a.w, v.w);
    *reinterpret_cast<float4*>(base + (long)t * H_) = hs;
  }
}

extern "C" void kernel_launch(void* const* d_in, const int* in_sizes, int n_in,
                              void* d_out, int out_size, void* d_ws, size_t ws_size,
                              hipStream_t stream) {
  const float* x    = (const float*)d_in[0];   // [8,2048,1024]
  const float* rawa = (const float*)d_in[1];   // [1024]
  const float* Bm   = (const float*)d_in[2];   // [1024,1024]
  const float* h0   = (const float*)d_in[3];   // [8,1024]
  float* u = (float*)d_out;                    // u then y, in place

  // Workspace layout — identical to the R2 run that passed (36 MiB):
  char* w = (char*)d_ws;
  unsigned short* xb = (unsigned short*)w;                               // 32 MiB
  unsigned short* Bb = (unsigned short*)(w + 33554432);                  // 2 MiB
  float* a_sig = (float*)(w + 33554432 + 2097152);                       // 4 KiB
  float* E     = (float*)(w + 33554432 + 2097152 + 4096);                // 1 MiB
  float* Cc    = (float*)(w + 33554432 + 2097152 + 4096 + 1048576);      // 1 MiB

  // convert + sigmoid: NX4 + NB4 + 256 sigmoid-quads = 4456704+256 -> 17409 blocks
  hipLaunchKernelGGL(k_convert, dim3(17409), dim3(256), 0, stream, x, Bm, rawa, xb, Bb, a_sig);
  hipLaunchKernelGGL(k_gemm, dim3(128, 8), dim3(256), 0, stream, xb, Bb, u);
  hipLaunchKernelGGL(k_seg_ends, dim3(NVC * SEG / 256), dim3(256), 0, stream, u, a_sig, E);
  hipLaunchKernelGGL(k_carries, dim3(32), dim3(256), 0, stream, E, h0, a_sig, Cc);
  hipLaunchKernelGGL(k_scan, dim3(NVC * SEG / 256), dim3(256), 0, stream, u, Cc, a_sig);
}